// Round 6
// baseline (6550.562 us; speedup 1.0000x reference)
//
#include <hip/hip_runtime.h>
#include <math.h>
#include <stdint.h>

#define NIMG 16
#define A_TOTAL 8732
#define NCLS 80
#define TL_CLS 81
#define CANVASF 300.0f
#define SCORE_THR 0.01f
#define IOU_THRF 0.45f
#define KCAND 400
#define KOUT 200
#define CAND_CAP 4096
#define NBIN 65536

__device__ __forceinline__ float clampf(float v, float lo, float hi) {
    return fminf(fmaxf(v, lo), hi);
}

// ---------------------------------------------------------------------------
// Fused implicit-GEMM conv over ALL 12 head convs, one dispatch. f64 VALU FMA
// (bit-stable vs np f64 ref). f32->f64 hoisted to LDS staging.
// STRIDED thread->output mapping (n = tx + 16*j, m = ty + 16*i): B reads are
// 16 consecutive f64 (32 banks, conflict-free, broadcast across ty groups);
// round-5's blocked mapping (n = tx*4+j) had 4-way conflicts on every read
// (SQ_LDS_BANK_CONFLICT 7.6e8 = ~22% of cycles). Per-output k-accumulation
// order is unchanged -> identical f64 bits -> absmax 0 preserved.
// cls jobs: TM=4 (64x64 tile). reg jobs: TM=1 (16x64). BK=16, 256 thr/blk.
// ---------------------------------------------------------------------------
struct ConvJobs {
    const float* feat[12];
    const float* wgt[12];
    const float* bias[12];
    float*       outp[12];
    int Cin[12], Hdim[12], M[12], tl[12], an[12], off[12], tm[12];
    int blkStart[12], nTiles[12];
    int nJobs;
    int pad;
};

template<int TM>
__device__ __forceinline__ void conv_body(
    const float* __restrict__ feat, const float* __restrict__ wgt,
    const float* __restrict__ bias, float* __restrict__ outbuf,
    int Cin, int Hd, int M, int tl, int an, int lvl_off,
    int n0, int m0, double (*Asb)[66], double (*Bsb)[66])
{
    const int K = Cin * 9;
    const int HW = Hd * Hd;
    const int N = NIMG * HW;
    const int tid = threadIdx.x;
    const int tx = tid & 15;   // n dir: owns n0 + tx + 16*j
    const int ty = tid >> 4;   // m dir: owns m0 + ty + 16*i

    // B staging mapping: one pixel per (tid & 63), 4 k's per (tid >> 6)
    const int bn = tid & 63;
    const int bk0 = (tid >> 6) * 4;
    const int ng = n0 + bn;
    const bool nvalid = ng < N;
    int bimg = 0, y0 = 0, x0 = 0;
    if (nvalid) { bimg = ng / HW; int p = ng - bimg * HW; y0 = p / Hd; x0 = p - y0 * Hd; }
    const float* fbase = feat + (size_t)bimg * Cin * HW;

    double acc[TM][4];
#pragma unroll
    for (int i = 0; i < TM; i++)
#pragma unroll
        for (int j = 0; j < 4; j++) acc[i][j] = 0.0;

    for (int k0 = 0; k0 < K; k0 += 16) {
        // ---- A tile: (TM*16) x 16 f32 weights -> f64 LDS [k][m] ----
        if (TM == 4) {
            int am = tid >> 2;
            int ak0 = (tid & 3) * 4;
            int mg = m0 + am;
            float4 av = make_float4(0.f, 0.f, 0.f, 0.f);
            if (mg < M) av = *(const float4*)(wgt + (size_t)mg * K + k0 + ak0);
            Asb[ak0 + 0][am] = (double)av.x;
            Asb[ak0 + 1][am] = (double)av.y;
            Asb[ak0 + 2][am] = (double)av.z;
            Asb[ak0 + 3][am] = (double)av.w;
        } else {  // TM == 1: 16 x 16 tile, one element per thread
            int am = tid & 15;
            int ak = tid >> 4;
            int mg = m0 + am;
            float v = (mg < M) ? wgt[(size_t)mg * K + k0 + ak] : 0.0f;
            Asb[ak][am] = (double)v;
        }
        // ---- B tile: 16 x 64 im2col -> f64 LDS [k][n] ----
#pragma unroll
        for (int e = 0; e < 4; e++) {
            int kg = k0 + bk0 + e;
            float v = 0.0f;
            if (nvalid) {
                int ci = kg / 9;
                int r = kg - ci * 9;
                int ky = r / 3;
                int kx = r - ky * 3;
                int yy = y0 + ky - 1;
                int xx = x0 + kx - 1;
                if (yy >= 0 && yy < Hd && xx >= 0 && xx < Hd)
                    v = fbase[(size_t)ci * HW + yy * Hd + xx];
            }
            Bsb[bk0 + e][bn] = (double)v;
        }
        __syncthreads();
        // ---- inner: pure f64 FMA, conflict-free LDS reads ----
#pragma unroll
        for (int kk = 0; kk < 16; kk++) {
            double b0 = Bsb[kk][tx + 0];
            double b1 = Bsb[kk][tx + 16];
            double b2 = Bsb[kk][tx + 32];
            double b3 = Bsb[kk][tx + 48];
#pragma unroll
            for (int i = 0; i < TM; i++) {
                double a = Asb[kk][ty + 16 * i];
                acc[i][0] = fma(a, b0, acc[i][0]);
                acc[i][1] = fma(a, b1, acc[i][1]);
                acc[i][2] = fma(a, b2, acc[i][2]);
                acc[i][3] = fma(a, b3, acc[i][3]);
            }
        }
        __syncthreads();
    }

    // ---- epilogue: scatter to [B, A_TOTAL, tl] ----
#pragma unroll
    for (int i = 0; i < TM; i++) {
        int mg = m0 + ty + 16 * i;
        if (mg >= M) continue;
        double bv = (double)bias[mg];
        int aidx = mg / tl;
        int t = mg - aidx * tl;
#pragma unroll
        for (int j = 0; j < 4; j++) {
            int ng2 = n0 + tx + 16 * j;
            if (ng2 >= N) continue;
            int b = ng2 / HW;
            int p = ng2 - b * HW;
            int row = lvl_off + p * an + aidx;
            outbuf[((size_t)b * A_TOTAL + row) * tl + t] = (float)(acc[i][j] + bv);
        }
    }
}

__global__ __launch_bounds__(256) void fused_conv(ConvJobs jobs)
{
    __shared__ double Asb[16][66];
    __shared__ double Bsb[16][66];

    // find job (block-uniform scan over <=12 entries)
    int bid = (int)blockIdx.x;
    int j = 0;
    while (j + 1 < jobs.nJobs && bid >= jobs.blkStart[j + 1]) j++;
    int rel = bid - jobs.blkStart[j];
    int nt = rel % jobs.nTiles[j];
    int mt = rel / jobs.nTiles[j];
    int n0 = nt * 64;

    if (jobs.tm[j] == 4) {
        conv_body<4>(jobs.feat[j], jobs.wgt[j], jobs.bias[j], jobs.outp[j],
                     jobs.Cin[j], jobs.Hdim[j], jobs.M[j], jobs.tl[j],
                     jobs.an[j], jobs.off[j], n0, mt * 64, Asb, Bsb);
    } else {
        conv_body<1>(jobs.feat[j], jobs.wgt[j], jobs.bias[j], jobs.outp[j],
                     jobs.Cin[j], jobs.Hdim[j], jobs.M[j], jobs.tl[j],
                     jobs.an[j], jobs.off[j], n0, mt * 16, Asb, Bsb);
    }
}

// ---------------------------------------------------------------------------
// Softmax over 81 classes (f64 internally), drop background class 0.
// ---------------------------------------------------------------------------
__global__ __launch_bounds__(256) void softmax_kernel(
    const float* __restrict__ cls, float* __restrict__ scr, int nrows)
{
    __shared__ float buf[64 * 81];
    __shared__ float inv[64];
    const int row0 = blockIdx.x * 64;
    const int tid = threadIdx.x;

    for (int i = tid; i < 64 * 81; i += 256) {
        int r = row0 + i / 81;
        buf[i] = (r < nrows) ? cls[(size_t)row0 * 81 + i] : 0.0f;
    }
    __syncthreads();
    if (tid < 64) {
        float m = -1e30f;
        for (int c = 0; c < 81; c++) m = fmaxf(m, buf[tid * 81 + c]);
        double md = (double)m;
        double ssum = 0.0;
        for (int c = 0; c < 81; c++) {
            double e = exp((double)buf[tid * 81 + c] - md);
            buf[tid * 81 + c] = (float)e;
            ssum += e;
        }
        inv[tid] = (float)(1.0 / ssum);
    }
    __syncthreads();
    for (int i = tid; i < 64 * 80; i += 256) {
        int r = i / 80;
        int c = i - r * 80;
        int gr = row0 + r;
        if (gr < nrows) scr[(size_t)gr * 80 + c] = buf[r * 81 + c + 1] * inv[r];
    }
}

// ---------------------------------------------------------------------------
__global__ void zero_kernel(unsigned int* __restrict__ p, int n)
{
    int i = blockIdx.x * blockDim.x + threadIdx.x;
    if (i < n) p[i] = 0u;
}

// ---------------------------------------------------------------------------
// Histogram of top-16 float bits per image (scores >= 0 so bits monotone)
// ---------------------------------------------------------------------------
__global__ void hist_kernel(const float* __restrict__ scr, unsigned int* __restrict__ hist)
{
    const int per_img = A_TOTAL * NCLS;   // 698560
    const size_t total = (size_t)NIMG * per_img;
    for (size_t i = (size_t)blockIdx.x * blockDim.x + threadIdx.x; i < total;
         i += (size_t)gridDim.x * blockDim.x) {
        float v = scr[i];
        if (v > SCORE_THR) {
            int img = (int)(i / per_img);
            unsigned int u = __float_as_uint(v);
            atomicAdd(&hist[img * NBIN + (u >> 16)], 1u);
        }
    }
}

// ---------------------------------------------------------------------------
// Find cutoff bin b0 = largest bin with cum(count of bins >= b0) >= 400
// ---------------------------------------------------------------------------
__global__ __launch_bounds__(1024) void select_kernel(
    const unsigned int* __restrict__ hist, unsigned int* __restrict__ sel)
{
    __shared__ unsigned int vals[1024];
    __shared__ unsigned int red[1024];
    __shared__ int s_total, s_b0, s_done;
    const int img = blockIdx.x;
    const int tid = threadIdx.x;
    if (tid == 0) { s_total = 0; s_b0 = 0; s_done = 0; }
    __syncthreads();
    for (int c = 63; c >= 0; c--) {
        unsigned int h = hist[img * NBIN + c * 1024 + tid];
        vals[tid] = h;
        red[tid] = h;
        __syncthreads();
        for (int s = 512; s > 0; s >>= 1) {
            if (tid < s) red[tid] += red[tid + s];
            __syncthreads();
        }
        if (tid == 0 && !s_done) {
            if (s_total + (int)red[0] >= KCAND) {
                int cum = s_total;
                for (int tt = 1023; tt >= 0; tt--) {
                    cum += (int)vals[tt];
                    if (cum >= KCAND) { s_b0 = c * 1024 + tt; s_done = 1; break; }
                }
            } else {
                s_total += (int)red[0];
            }
        }
        __syncthreads();
        if (s_done) break;
    }
    if (tid == 0) sel[img] = (unsigned int)s_b0;
}

// ---------------------------------------------------------------------------
// Gather candidates with prefix >= b0 into per-image list (bits, idx)
// ---------------------------------------------------------------------------
__global__ void gather_kernel(const float* __restrict__ scr,
                              const unsigned int* __restrict__ sel,
                              unsigned int* __restrict__ candcnt,
                              uint2* __restrict__ cand)
{
    const int per_img = A_TOTAL * NCLS;
    const size_t total = (size_t)NIMG * per_img;
    for (size_t i = (size_t)blockIdx.x * blockDim.x + threadIdx.x; i < total;
         i += (size_t)gridDim.x * blockDim.x) {
        float v = scr[i];
        if (v > SCORE_THR) {
            int img = (int)(i / per_img);
            unsigned int u = __float_as_uint(v);
            if ((u >> 16) >= sel[img]) {
                unsigned int pos = atomicAdd(&candcnt[img], 1u);
                if (pos < CAND_CAP) {
                    unsigned int ridx = (unsigned int)(i - (size_t)img * per_img);
                    cand[(size_t)img * CAND_CAP + pos] = make_uint2(u, ridx);
                }
            }
        }
    }
}

// ---------------------------------------------------------------------------
// Per image: bitonic sort candidates (desc score, asc idx tie-break), take
// 400, decode (f32 ops mimicking np, exp in f64), greedy class-aware NMS
// (f32 mimicking np incl. offset-add quantization), emit top-200.
// ---------------------------------------------------------------------------
__global__ __launch_bounds__(1024) void nms_kernel(
    const uint2* __restrict__ cand, const unsigned int* __restrict__ candcnt,
    const float* __restrict__ reg_all, const float* __restrict__ priors,
    float* __restrict__ out)
{
    __shared__ unsigned long long key[CAND_CAP];
    __shared__ float s_sc[KCAND];
    __shared__ float s_bx[KCAND][4];
    __shared__ float s_ob[KCAND][4];
    __shared__ float s_ar[KCAND];
    __shared__ float s_cl[KCAND];
    __shared__ int s_keep[KCAND];
    __shared__ int s_fi[KOUT];

    const int img = blockIdx.x;
    const int tid = threadIdx.x;
    unsigned int craw = candcnt[img];
    const int cnt = (craw > CAND_CAP) ? CAND_CAP : (int)craw;

    for (int i = tid; i < CAND_CAP; i += 1024) {
        unsigned long long kv = 0ull;
        if (i < cnt) {
            uint2 e = cand[(size_t)img * CAND_CAP + i];
            kv = ((unsigned long long)e.x << 32) | (unsigned int)(~e.y);
        }
        key[i] = kv;
    }
    __syncthreads();

    // bitonic sort, descending
    for (int ksz = 2; ksz <= CAND_CAP; ksz <<= 1) {
        for (int jj = ksz >> 1; jj > 0; jj >>= 1) {
            for (int i = tid; i < CAND_CAP; i += 1024) {
                int p = i ^ jj;
                if (p > i) {
                    bool desc = ((i & ksz) == 0);
                    unsigned long long a = key[i];
                    unsigned long long b = key[p];
                    bool sw = desc ? (a < b) : (a > b);
                    if (sw) { key[i] = b; key[p] = a; }
                }
            }
            __syncthreads();
        }
    }

    // decode top-400 (f32 op chain identical to the reference's)
    const float CLIPF = 4.135166556742356f;  // (float)log(1000/16)
    if (tid < KCAND) {
        const int j = tid;
        float s = 0.0f;
        unsigned int idx = 0u;
        if (j < cnt) {
            unsigned long long kv = key[j];
            unsigned int bits = (unsigned int)(kv >> 32);
            idx = ~((unsigned int)kv);
            s = __uint_as_float(bits);
        }
        int anc = (int)(idx / NCLS);
        int cl = (int)(idx - (unsigned int)anc * NCLS) + 1;
        const float* d = reg_all + ((size_t)img * A_TOTAL + anc) * 4;
        const float* pr = priors + (size_t)anc * 4;
        float d0 = d[0], d1 = d[1], d2 = d[2], d3 = d[3];
        float p0 = pr[0], p1 = pr[1], p2 = pr[2], p3 = pr[3];
        float cx = p0 + d0 * 0.1f * p2;
        float cy = p1 + d1 * 0.1f * p3;
        float t2 = fminf(d2 * 0.2f, CLIPF);
        float t3 = fminf(d3 * 0.2f, CLIPF);
        float bw = p2 * (float)exp((double)t2);   // exp correctly rounded to f32
        float bh = p3 * (float)exp((double)t3);
        float x1 = clampf(cx - 0.5f * bw, 0.0f, CANVASF);
        float y1 = clampf(cy - 0.5f * bh, 0.0f, CANVASF);
        float x2 = clampf(cx + 0.5f * bw, 0.0f, CANVASF);
        float y2 = clampf(cy + 0.5f * bh, 0.0f, CANVASF);
        bool valid = (s > 0.0f) && (x2 > x1) && (y2 > y1);
        s = valid ? s : 0.0f;
        float off = (float)cl * (CANVASF + 1.0f);
        float ox1 = x1 + off, oy1 = y1 + off, ox2 = x2 + off, oy2 = y2 + off;
        s_sc[j] = s;
        s_cl[j] = (float)cl;
        s_keep[j] = valid ? 1 : 0;
        s_bx[j][0] = x1; s_bx[j][1] = y1; s_bx[j][2] = x2; s_bx[j][3] = y2;
        s_ob[j][0] = ox1; s_ob[j][1] = oy1; s_ob[j][2] = ox2; s_ob[j][3] = oy2;
        s_ar[j] = (ox2 - ox1) * (oy2 - oy1);
    }
    __syncthreads();

    // greedy NMS, exactly matching reference f32 semantics
    for (int i = 0; i < KCAND; i++) {
        int ki = s_keep[i];
        if (ki && tid < KCAND && tid > i) {
            float lx = fmaxf(s_ob[i][0], s_ob[tid][0]);
            float ly = fmaxf(s_ob[i][1], s_ob[tid][1]);
            float rx = fminf(s_ob[i][2], s_ob[tid][2]);
            float ry = fminf(s_ob[i][3], s_ob[tid][3]);
            float iw = fmaxf(rx - lx, 0.0f);
            float ih = fmaxf(ry - ly, 0.0f);
            float inter = iw * ih;
            float iou = inter / (s_ar[i] + s_ar[tid] - inter + 1e-9f);
            if (iou > IOU_THRF) s_keep[tid] = 0;
        }
        __syncthreads();
    }

    // final top-200: kept (sorted desc) first, then suppressed by index asc
    if (tid == 0) {
        int pos = 0;
        for (int j = 0; j < KCAND && pos < KOUT; j++)
            if (s_keep[j]) s_fi[pos++] = j;
        for (int j = 0; j < KCAND && pos < KOUT; j++)
            if (!s_keep[j]) s_fi[pos++] = j;
    }
    __syncthreads();

    if (tid < KOUT) {
        int j = s_fi[tid];
        float fs = s_keep[j] ? s_sc[j] : 0.0f;
        size_t o = (size_t)img * KOUT + tid;
        out[o * 4 + 0] = s_bx[j][0];
        out[o * 4 + 1] = s_bx[j][1];
        out[o * 4 + 2] = s_bx[j][2];
        out[o * 4 + 3] = s_bx[j][3];
        out[(size_t)NIMG * KOUT * 4 + o] = fs;
        out[(size_t)NIMG * KOUT * 5 + o] = (fs > 0.0f) ? s_cl[j] : 0.0f;
    }
}

// ---------------------------------------------------------------------------
extern "C" void kernel_launch(void* const* d_in, const int* in_sizes, int n_in,
                              void* d_out, int out_size, void* d_ws, size_t ws_size,
                              hipStream_t stream)
{
    static const int Cin_[6] = {512, 1024, 512, 256, 256, 256};
    static const int HW_[6]  = {38, 19, 10, 5, 3, 1};
    static const int an_[6]  = {4, 6, 6, 6, 4, 4};
    static const int off_[6] = {0, 5776, 7942, 8542, 8692, 8728};

    char* ws = (char*)d_ws;
    const size_t OFF_CLS  = 0;                         // 16*8732*81*4 = 45,266,688
    const size_t OFF_SCR  = 45266688;                  // 16*8732*80*4 = 44,707,840
    const size_t OFF_REG  = 89974528;                  // 16*8732*4*4  =  2,235,392
    const size_t OFF_HIST = 92209920;                  // 16*65536*4   =  4,194,304
    const size_t OFF_CCNT = 96404224;                  // 16*4
    const size_t OFF_SEL  = 96404288;                  // 16*4
    const size_t OFF_CAND = 96404352;                  // 16*4096*8 = 524,288

    float* cls_all = (float*)(ws + OFF_CLS);
    float* scr     = (float*)(ws + OFF_SCR);
    float* reg_all = (float*)(ws + OFF_REG);
    unsigned int* hist    = (unsigned int*)(ws + OFF_HIST);
    unsigned int* candcnt = (unsigned int*)(ws + OFF_CCNT);
    unsigned int* sel     = (unsigned int*)(ws + OFF_SEL);
    uint2* cand           = (uint2*)(ws + OFF_CAND);

    {
        int nz = NIMG * NBIN + 16 + 16;
        zero_kernel<<<(nz + 255) / 256, 256, 0, stream>>>(hist, nz);
    }

    // ---- build fused conv job table (big-K jobs first) ----
    ConvJobs jobs;
    static const int ord_lvl[12]  = {1, 0, 1, 0, 2, 2, 3, 3, 4, 4, 5, 5};
    static const int ord_iscls[12]= {1, 1, 0, 0, 1, 0, 1, 0, 1, 0, 1, 0};
    int blk = 0;
    for (int q = 0; q < 12; q++) {
        int L = ord_lvl[q];
        int iscls = ord_iscls[q];
        int an = an_[L];
        jobs.feat[q] = (const float*)d_in[L * 5 + 0];
        jobs.wgt[q]  = (const float*)d_in[L * 5 + (iscls ? 1 : 3)];
        jobs.bias[q] = (const float*)d_in[L * 5 + (iscls ? 2 : 4)];
        jobs.outp[q] = iscls ? cls_all : reg_all;
        jobs.Cin[q]  = Cin_[L];
        jobs.Hdim[q] = HW_[L];
        jobs.M[q]    = an * (iscls ? TL_CLS : 4);
        jobs.tl[q]   = iscls ? TL_CLS : 4;
        jobs.an[q]   = an;
        jobs.off[q]  = off_[L];
        jobs.tm[q]   = iscls ? 4 : 1;
        int N = NIMG * HW_[L] * HW_[L];
        int bm = jobs.tm[q] * 16;
        int nT = (N + 63) / 64;
        int mT = (jobs.M[q] + bm - 1) / bm;
        jobs.blkStart[q] = blk;
        jobs.nTiles[q] = nT;
        blk += nT * mT;
    }
    jobs.nJobs = 12;
    jobs.pad = 0;

    fused_conv<<<blk, 256, 0, stream>>>(jobs);

    softmax_kernel<<<(NIMG * A_TOTAL + 63) / 64, 256, 0, stream>>>(cls_all, scr, NIMG * A_TOTAL);
    hist_kernel<<<2048, 256, 0, stream>>>(scr, hist);
    select_kernel<<<NIMG, 1024, 0, stream>>>(hist, sel);
    gather_kernel<<<2048, 256, 0, stream>>>(scr, sel, candcnt, cand);
    nms_kernel<<<NIMG, 1024, 0, stream>>>(cand, candcnt, reg_all,
                                          (const float*)d_in[30], (float*)d_out);
}

// Round 7
// 5693.850 us; speedup vs baseline: 1.1505x; 1.1505x over previous
//
#include <hip/hip_runtime.h>
#include <math.h>
#include <stdint.h>

#define NIMG 16
#define A_TOTAL 8732
#define NCLS 80
#define TL_CLS 81
#define CANVASF 300.0f
#define SCORE_THR 0.01f
#define IOU_THRF 0.45f
#define KCAND 400
#define KOUT 200
#define CAND_CAP 4096
#define NBIN 65536

typedef double d4 __attribute__((ext_vector_type(4)));

__device__ __forceinline__ float clampf(float v, float lo, float hi) {
    return fminf(fmaxf(v, lo), hi);
}

// ---------------------------------------------------------------------------
// Fused conv dispatch, two compute paths:
//  - cls heads (95% of FLOPs): f64 MFMA (v_mfma_f64_16x16x4) with runtime
//    probe-calibrated C/D layout (round 4: proven bit-exact, absmax 0.0).
//    MFMA needs only 2 ds_read_b64 per 2048 FLOP -> escapes the LDS-issue
//    bound that capped the VALU-f64 path (rounds 5/6 at ~24 TF).
//  - reg heads (5%): VALU f64 path (rounds 5/6, proven bit-exact).
// Both in ONE dispatch (round 5's fusion), jobs big-first.
// BM=64 (cls, 4 waves stacked in m) / 16 (reg); BN=64; BK=16.
// ---------------------------------------------------------------------------
struct ConvJobs {
    const float* feat[12];
    const float* wgt[12];
    const float* bias[12];
    float*       outp[12];
    int Cin[12], Hdim[12], M[12], tl[12], an[12], off[12], tm[12];
    int blkStart[12], nTiles[12];
    int nJobs;
    int pad;
};

// ---- staging helper: B tile 16 x 64 im2col -> f64 LDS [k][n] ----
__device__ __forceinline__ void stage_B(
    const float* __restrict__ fbase, bool nvalid, int y0, int x0,
    int Hd, int HW, int k0, int bk0, int bn, double (*Bsb)[68])
{
#pragma unroll
    for (int e = 0; e < 4; e++) {
        int kg = k0 + bk0 + e;
        float v = 0.0f;
        if (nvalid) {
            int ci = kg / 9;
            int r = kg - ci * 9;
            int ky = r / 3;
            int kx = r - ky * 3;
            int yy = y0 + ky - 1;
            int xx = x0 + kx - 1;
            if (yy >= 0 && yy < Hd && xx >= 0 && xx < Hd)
                v = fbase[(size_t)ci * HW + yy * Hd + xx];
        }
        Bsb[bk0 + e][bn] = (double)v;
    }
}

// ---- cls path: f64 MFMA, per wave 16m x 64n as 4 chains ----
__device__ __forceinline__ void conv_body_mfma(
    const float* __restrict__ feat, const float* __restrict__ wgt,
    const float* __restrict__ bias, float* __restrict__ outbuf,
    int Cin, int Hd, int M, int tl, int an, int lvl_off,
    int n0, int m0, double (*Asb)[68], double (*Bsb)[68])
{
    const int K = Cin * 9;
    const int HW = Hd * Hd;
    const int N = NIMG * HW;
    const int tid = threadIdx.x;
    const int wave = tid >> 6;
    const int lane = tid & 63;
    const int lm = lane & 15;
    const int lk = lane >> 4;

    // layout self-calibration (round 4, proven): recover (row, col) per slot
    int rowIdx[4], colIdx[4];
    {
        d4 z = (d4){0.0, 0.0, 0.0, 0.0};
        d4 pr = __builtin_amdgcn_mfma_f64_16x16x4f64((double)lm, 1.0, z, 0, 0, 0);
        d4 pc = __builtin_amdgcn_mfma_f64_16x16x4f64(1.0, (double)lm, z, 0, 0, 0);
#pragma unroll
        for (int i = 0; i < 4; i++) {
            rowIdx[i] = (int)(pr[i] * 0.25 + 0.5);
            colIdx[i] = (int)(pc[i] * 0.25 + 0.5);
        }
    }

    const int bn = tid & 63;
    const int bk0 = (tid >> 6) * 4;
    const int ng = n0 + bn;
    const bool nvalid = ng < N;
    int bimg = 0, y0 = 0, x0 = 0;
    if (nvalid) { bimg = ng / HW; int p = ng - bimg * HW; y0 = p / Hd; x0 = p - y0 * Hd; }
    const float* fbase = feat + (size_t)bimg * Cin * HW;

    d4 acc[4];
#pragma unroll
    for (int i = 0; i < 4; i++) acc[i] = (d4){0.0, 0.0, 0.0, 0.0};

    for (int k0 = 0; k0 < K; k0 += 16) {
        // A tile: 64 x 16 f32 weights -> f64 LDS [k][m]
        {
            int am = tid >> 2;
            int ak0 = (tid & 3) * 4;
            int mg = m0 + am;
            float4 av = make_float4(0.f, 0.f, 0.f, 0.f);
            if (mg < M) av = *(const float4*)(wgt + (size_t)mg * K + k0 + ak0);
            Asb[ak0 + 0][am] = (double)av.x;
            Asb[ak0 + 1][am] = (double)av.y;
            Asb[ak0 + 2][am] = (double)av.z;
            Asb[ak0 + 3][am] = (double)av.w;
        }
        stage_B(fbase, nvalid, y0, x0, Hd, HW, k0, bk0, bn, Bsb);
        __syncthreads();
#pragma unroll
        for (int ks = 0; ks < 16; ks += 4) {
            double a  = Asb[ks + lk][wave * 16 + lm];
            double b0 = Bsb[ks + lk][ 0 + lm];
            double b1 = Bsb[ks + lk][16 + lm];
            double b2 = Bsb[ks + lk][32 + lm];
            double b3 = Bsb[ks + lk][48 + lm];
            acc[0] = __builtin_amdgcn_mfma_f64_16x16x4f64(a, b0, acc[0], 0, 0, 0);
            acc[1] = __builtin_amdgcn_mfma_f64_16x16x4f64(a, b1, acc[1], 0, 0, 0);
            acc[2] = __builtin_amdgcn_mfma_f64_16x16x4f64(a, b2, acc[2], 0, 0, 0);
            acc[3] = __builtin_amdgcn_mfma_f64_16x16x4f64(a, b3, acc[3], 0, 0, 0);
        }
        __syncthreads();
    }

    // epilogue: probe-derived (row, col) per slot
#pragma unroll
    for (int c = 0; c < 4; c++) {
#pragma unroll
        for (int i = 0; i < 4; i++) {
            int mg  = m0 + wave * 16 + rowIdx[i];
            int ng2 = n0 + c * 16 + colIdx[i];
            if (mg >= M || ng2 >= N) continue;
            int b = ng2 / HW;
            int p = ng2 - b * HW;
            int aidx = mg / tl;
            int t = mg - aidx * tl;
            int row = lvl_off + p * an + aidx;
            outbuf[((size_t)b * A_TOTAL + row) * tl + t] = (float)(acc[c][i] + (double)bias[mg]);
        }
    }
}

// ---- reg path: VALU f64, 16m x 64n, one output row per ty ----
__device__ __forceinline__ void conv_body_valu(
    const float* __restrict__ feat, const float* __restrict__ wgt,
    const float* __restrict__ bias, float* __restrict__ outbuf,
    int Cin, int Hd, int M, int tl, int an, int lvl_off,
    int n0, int m0, double (*Asb)[68], double (*Bsb)[68])
{
    const int K = Cin * 9;
    const int HW = Hd * Hd;
    const int N = NIMG * HW;
    const int tid = threadIdx.x;
    const int tx = tid & 15;
    const int ty = tid >> 4;

    const int bn = tid & 63;
    const int bk0 = (tid >> 6) * 4;
    const int ng = n0 + bn;
    const bool nvalid = ng < N;
    int bimg = 0, y0 = 0, x0 = 0;
    if (nvalid) { bimg = ng / HW; int p = ng - bimg * HW; y0 = p / Hd; x0 = p - y0 * Hd; }
    const float* fbase = feat + (size_t)bimg * Cin * HW;

    double acc[4];
#pragma unroll
    for (int j = 0; j < 4; j++) acc[j] = 0.0;

    for (int k0 = 0; k0 < K; k0 += 16) {
        {
            int am = tid & 15;
            int ak = tid >> 4;
            int mg = m0 + am;
            float v = (mg < M) ? wgt[(size_t)mg * K + k0 + ak] : 0.0f;
            Asb[ak][am] = (double)v;
        }
        stage_B(fbase, nvalid, y0, x0, Hd, HW, k0, bk0, bn, Bsb);
        __syncthreads();
#pragma unroll
        for (int kk = 0; kk < 16; kk++) {
            double a = Asb[kk][ty];
            double b0 = Bsb[kk][tx + 0];
            double b1 = Bsb[kk][tx + 16];
            double b2 = Bsb[kk][tx + 32];
            double b3 = Bsb[kk][tx + 48];
            acc[0] = fma(a, b0, acc[0]);
            acc[1] = fma(a, b1, acc[1]);
            acc[2] = fma(a, b2, acc[2]);
            acc[3] = fma(a, b3, acc[3]);
        }
        __syncthreads();
    }

    int mg = m0 + ty;
    if (mg < M) {
        double bv = (double)bias[mg];
        int aidx = mg / tl;
        int t = mg - aidx * tl;
#pragma unroll
        for (int j = 0; j < 4; j++) {
            int ng2 = n0 + tx + 16 * j;
            if (ng2 >= N) continue;
            int b = ng2 / HW;
            int p = ng2 - b * HW;
            int row = lvl_off + p * an + aidx;
            outbuf[((size_t)b * A_TOTAL + row) * tl + t] = (float)(acc[j] + bv);
        }
    }
}

__global__ __launch_bounds__(256) void fused_conv(ConvJobs jobs)
{
    __shared__ double Asb[16][68];
    __shared__ double Bsb[16][68];

    int bid = (int)blockIdx.x;
    int j = 0;
    while (j + 1 < jobs.nJobs && bid >= jobs.blkStart[j + 1]) j++;
    int rel = bid - jobs.blkStart[j];
    int nt = rel % jobs.nTiles[j];
    int mt = rel / jobs.nTiles[j];
    int n0 = nt * 64;

    if (jobs.tm[j] == 4) {
        conv_body_mfma(jobs.feat[j], jobs.wgt[j], jobs.bias[j], jobs.outp[j],
                       jobs.Cin[j], jobs.Hdim[j], jobs.M[j], jobs.tl[j],
                       jobs.an[j], jobs.off[j], n0, mt * 64, Asb, Bsb);
    } else {
        conv_body_valu(jobs.feat[j], jobs.wgt[j], jobs.bias[j], jobs.outp[j],
                       jobs.Cin[j], jobs.Hdim[j], jobs.M[j], jobs.tl[j],
                       jobs.an[j], jobs.off[j], n0, mt * 16, Asb, Bsb);
    }
}

// ---------------------------------------------------------------------------
// Softmax over 81 classes (f64 internally), drop background class 0.
// ---------------------------------------------------------------------------
__global__ __launch_bounds__(256) void softmax_kernel(
    const float* __restrict__ cls, float* __restrict__ scr, int nrows)
{
    __shared__ float buf[64 * 81];
    __shared__ float inv[64];
    const int row0 = blockIdx.x * 64;
    const int tid = threadIdx.x;

    for (int i = tid; i < 64 * 81; i += 256) {
        int r = row0 + i / 81;
        buf[i] = (r < nrows) ? cls[(size_t)row0 * 81 + i] : 0.0f;
    }
    __syncthreads();
    if (tid < 64) {
        float m = -1e30f;
        for (int c = 0; c < 81; c++) m = fmaxf(m, buf[tid * 81 + c]);
        double md = (double)m;
        double ssum = 0.0;
        for (int c = 0; c < 81; c++) {
            double e = exp((double)buf[tid * 81 + c] - md);
            buf[tid * 81 + c] = (float)e;
            ssum += e;
        }
        inv[tid] = (float)(1.0 / ssum);
    }
    __syncthreads();
    for (int i = tid; i < 64 * 80; i += 256) {
        int r = i / 80;
        int c = i - r * 80;
        int gr = row0 + r;
        if (gr < nrows) scr[(size_t)gr * 80 + c] = buf[r * 81 + c + 1] * inv[r];
    }
}

// ---------------------------------------------------------------------------
__global__ void zero_kernel(unsigned int* __restrict__ p, int n)
{
    int i = blockIdx.x * blockDim.x + threadIdx.x;
    if (i < n) p[i] = 0u;
}

// ---------------------------------------------------------------------------
__global__ void hist_kernel(const float* __restrict__ scr, unsigned int* __restrict__ hist)
{
    const int per_img = A_TOTAL * NCLS;
    const size_t total = (size_t)NIMG * per_img;
    for (size_t i = (size_t)blockIdx.x * blockDim.x + threadIdx.x; i < total;
         i += (size_t)gridDim.x * blockDim.x) {
        float v = scr[i];
        if (v > SCORE_THR) {
            int img = (int)(i / per_img);
            unsigned int u = __float_as_uint(v);
            atomicAdd(&hist[img * NBIN + (u >> 16)], 1u);
        }
    }
}

// ---------------------------------------------------------------------------
__global__ __launch_bounds__(1024) void select_kernel(
    const unsigned int* __restrict__ hist, unsigned int* __restrict__ sel)
{
    __shared__ unsigned int vals[1024];
    __shared__ unsigned int red[1024];
    __shared__ int s_total, s_b0, s_done;
    const int img = blockIdx.x;
    const int tid = threadIdx.x;
    if (tid == 0) { s_total = 0; s_b0 = 0; s_done = 0; }
    __syncthreads();
    for (int c = 63; c >= 0; c--) {
        unsigned int h = hist[img * NBIN + c * 1024 + tid];
        vals[tid] = h;
        red[tid] = h;
        __syncthreads();
        for (int s = 512; s > 0; s >>= 1) {
            if (tid < s) red[tid] += red[tid + s];
            __syncthreads();
        }
        if (tid == 0 && !s_done) {
            if (s_total + (int)red[0] >= KCAND) {
                int cum = s_total;
                for (int tt = 1023; tt >= 0; tt--) {
                    cum += (int)vals[tt];
                    if (cum >= KCAND) { s_b0 = c * 1024 + tt; s_done = 1; break; }
                }
            } else {
                s_total += (int)red[0];
            }
        }
        __syncthreads();
        if (s_done) break;
    }
    if (tid == 0) sel[img] = (unsigned int)s_b0;
}

// ---------------------------------------------------------------------------
__global__ void gather_kernel(const float* __restrict__ scr,
                              const unsigned int* __restrict__ sel,
                              unsigned int* __restrict__ candcnt,
                              uint2* __restrict__ cand)
{
    const int per_img = A_TOTAL * NCLS;
    const size_t total = (size_t)NIMG * per_img;
    for (size_t i = (size_t)blockIdx.x * blockDim.x + threadIdx.x; i < total;
         i += (size_t)gridDim.x * blockDim.x) {
        float v = scr[i];
        if (v > SCORE_THR) {
            int img = (int)(i / per_img);
            unsigned int u = __float_as_uint(v);
            if ((u >> 16) >= sel[img]) {
                unsigned int pos = atomicAdd(&candcnt[img], 1u);
                if (pos < CAND_CAP) {
                    unsigned int ridx = (unsigned int)(i - (size_t)img * per_img);
                    cand[(size_t)img * CAND_CAP + pos] = make_uint2(u, ridx);
                }
            }
        }
    }
}

// ---------------------------------------------------------------------------
__global__ __launch_bounds__(1024) void nms_kernel(
    const uint2* __restrict__ cand, const unsigned int* __restrict__ candcnt,
    const float* __restrict__ reg_all, const float* __restrict__ priors,
    float* __restrict__ out)
{
    __shared__ unsigned long long key[CAND_CAP];
    __shared__ float s_sc[KCAND];
    __shared__ float s_bx[KCAND][4];
    __shared__ float s_ob[KCAND][4];
    __shared__ float s_ar[KCAND];
    __shared__ float s_cl[KCAND];
    __shared__ int s_keep[KCAND];
    __shared__ int s_fi[KOUT];

    const int img = blockIdx.x;
    const int tid = threadIdx.x;
    unsigned int craw = candcnt[img];
    const int cnt = (craw > CAND_CAP) ? CAND_CAP : (int)craw;

    for (int i = tid; i < CAND_CAP; i += 1024) {
        unsigned long long kv = 0ull;
        if (i < cnt) {
            uint2 e = cand[(size_t)img * CAND_CAP + i];
            kv = ((unsigned long long)e.x << 32) | (unsigned int)(~e.y);
        }
        key[i] = kv;
    }
    __syncthreads();

    for (int ksz = 2; ksz <= CAND_CAP; ksz <<= 1) {
        for (int jj = ksz >> 1; jj > 0; jj >>= 1) {
            for (int i = tid; i < CAND_CAP; i += 1024) {
                int p = i ^ jj;
                if (p > i) {
                    bool desc = ((i & ksz) == 0);
                    unsigned long long a = key[i];
                    unsigned long long b = key[p];
                    bool sw = desc ? (a < b) : (a > b);
                    if (sw) { key[i] = b; key[p] = a; }
                }
            }
            __syncthreads();
        }
    }

    const float CLIPF = 4.135166556742356f;
    if (tid < KCAND) {
        const int j = tid;
        float s = 0.0f;
        unsigned int idx = 0u;
        if (j < cnt) {
            unsigned long long kv = key[j];
            unsigned int bits = (unsigned int)(kv >> 32);
            idx = ~((unsigned int)kv);
            s = __uint_as_float(bits);
        }
        int anc = (int)(idx / NCLS);
        int cl = (int)(idx - (unsigned int)anc * NCLS) + 1;
        const float* d = reg_all + ((size_t)img * A_TOTAL + anc) * 4;
        const float* pr = priors + (size_t)anc * 4;
        float d0 = d[0], d1 = d[1], d2 = d[2], d3 = d[3];
        float p0 = pr[0], p1 = pr[1], p2 = pr[2], p3 = pr[3];
        float cx = p0 + d0 * 0.1f * p2;
        float cy = p1 + d1 * 0.1f * p3;
        float t2 = fminf(d2 * 0.2f, CLIPF);
        float t3 = fminf(d3 * 0.2f, CLIPF);
        float bw = p2 * (float)exp((double)t2);
        float bh = p3 * (float)exp((double)t3);
        float x1 = clampf(cx - 0.5f * bw, 0.0f, CANVASF);
        float y1 = clampf(cy - 0.5f * bh, 0.0f, CANVASF);
        float x2 = clampf(cx + 0.5f * bw, 0.0f, CANVASF);
        float y2 = clampf(cy + 0.5f * bh, 0.0f, CANVASF);
        bool valid = (s > 0.0f) && (x2 > x1) && (y2 > y1);
        s = valid ? s : 0.0f;
        float off = (float)cl * (CANVASF + 1.0f);
        float ox1 = x1 + off, oy1 = y1 + off, ox2 = x2 + off, oy2 = y2 + off;
        s_sc[j] = s;
        s_cl[j] = (float)cl;
        s_keep[j] = valid ? 1 : 0;
        s_bx[j][0] = x1; s_bx[j][1] = y1; s_bx[j][2] = x2; s_bx[j][3] = y2;
        s_ob[j][0] = ox1; s_ob[j][1] = oy1; s_ob[j][2] = ox2; s_ob[j][3] = oy2;
        s_ar[j] = (ox2 - ox1) * (oy2 - oy1);
    }
    __syncthreads();

    for (int i = 0; i < KCAND; i++) {
        int ki = s_keep[i];
        if (ki && tid < KCAND && tid > i) {
            float lx = fmaxf(s_ob[i][0], s_ob[tid][0]);
            float ly = fmaxf(s_ob[i][1], s_ob[tid][1]);
            float rx = fminf(s_ob[i][2], s_ob[tid][2]);
            float ry = fminf(s_ob[i][3], s_ob[tid][3]);
            float iw = fmaxf(rx - lx, 0.0f);
            float ih = fmaxf(ry - ly, 0.0f);
            float inter = iw * ih;
            float iou = inter / (s_ar[i] + s_ar[tid] - inter + 1e-9f);
            if (iou > IOU_THRF) s_keep[tid] = 0;
        }
        __syncthreads();
    }

    if (tid == 0) {
        int pos = 0;
        for (int j = 0; j < KCAND && pos < KOUT; j++)
            if (s_keep[j]) s_fi[pos++] = j;
        for (int j = 0; j < KCAND && pos < KOUT; j++)
            if (!s_keep[j]) s_fi[pos++] = j;
    }
    __syncthreads();

    if (tid < KOUT) {
        int j = s_fi[tid];
        float fs = s_keep[j] ? s_sc[j] : 0.0f;
        size_t o = (size_t)img * KOUT + tid;
        out[o * 4 + 0] = s_bx[j][0];
        out[o * 4 + 1] = s_bx[j][1];
        out[o * 4 + 2] = s_bx[j][2];
        out[o * 4 + 3] = s_bx[j][3];
        out[(size_t)NIMG * KOUT * 4 + o] = fs;
        out[(size_t)NIMG * KOUT * 5 + o] = (fs > 0.0f) ? s_cl[j] : 0.0f;
    }
}

// ---------------------------------------------------------------------------
extern "C" void kernel_launch(void* const* d_in, const int* in_sizes, int n_in,
                              void* d_out, int out_size, void* d_ws, size_t ws_size,
                              hipStream_t stream)
{
    static const int Cin_[6] = {512, 1024, 512, 256, 256, 256};
    static const int HW_[6]  = {38, 19, 10, 5, 3, 1};
    static const int an_[6]  = {4, 6, 6, 6, 4, 4};
    static const int off_[6] = {0, 5776, 7942, 8542, 8692, 8728};

    char* ws = (char*)d_ws;
    const size_t OFF_CLS  = 0;
    const size_t OFF_SCR  = 45266688;
    const size_t OFF_REG  = 89974528;
    const size_t OFF_HIST = 92209920;
    const size_t OFF_CCNT = 96404224;
    const size_t OFF_SEL  = 96404288;
    const size_t OFF_CAND = 96404352;

    float* cls_all = (float*)(ws + OFF_CLS);
    float* scr     = (float*)(ws + OFF_SCR);
    float* reg_all = (float*)(ws + OFF_REG);
    unsigned int* hist    = (unsigned int*)(ws + OFF_HIST);
    unsigned int* candcnt = (unsigned int*)(ws + OFF_CCNT);
    unsigned int* sel     = (unsigned int*)(ws + OFF_SEL);
    uint2* cand           = (uint2*)(ws + OFF_CAND);

    {
        int nz = NIMG * NBIN + 16 + 16;
        zero_kernel<<<(nz + 255) / 256, 256, 0, stream>>>(hist, nz);
    }

    ConvJobs jobs;
    static const int ord_lvl[12]  = {1, 0, 1, 0, 2, 2, 3, 3, 4, 4, 5, 5};
    static const int ord_iscls[12]= {1, 1, 0, 0, 1, 0, 1, 0, 1, 0, 1, 0};
    int blk = 0;
    for (int q = 0; q < 12; q++) {
        int L = ord_lvl[q];
        int iscls = ord_iscls[q];
        int an = an_[L];
        jobs.feat[q] = (const float*)d_in[L * 5 + 0];
        jobs.wgt[q]  = (const float*)d_in[L * 5 + (iscls ? 1 : 3)];
        jobs.bias[q] = (const float*)d_in[L * 5 + (iscls ? 2 : 4)];
        jobs.outp[q] = iscls ? cls_all : reg_all;
        jobs.Cin[q]  = Cin_[L];
        jobs.Hdim[q] = HW_[L];
        jobs.M[q]    = an * (iscls ? TL_CLS : 4);
        jobs.tl[q]   = iscls ? TL_CLS : 4;
        jobs.an[q]   = an;
        jobs.off[q]  = off_[L];
        jobs.tm[q]   = iscls ? 4 : 1;
        int N = NIMG * HW_[L] * HW_[L];
        int bm = jobs.tm[q] * 16;
        int nT = (N + 63) / 64;
        int mT = (jobs.M[q] + bm - 1) / bm;
        jobs.blkStart[q] = blk;
        jobs.nTiles[q] = nT;
        blk += nT * mT;
    }
    jobs.nJobs = 12;
    jobs.pad = 0;

    fused_conv<<<blk, 256, 0, stream>>>(jobs);

    softmax_kernel<<<(NIMG * A_TOTAL + 63) / 64, 256, 0, stream>>>(cls_all, scr, NIMG * A_TOTAL);
    hist_kernel<<<2048, 256, 0, stream>>>(scr, hist);
    select_kernel<<<NIMG, 1024, 0, stream>>>(hist, sel);
    gather_kernel<<<2048, 256, 0, stream>>>(scr, sel, candcnt, cand);
    nms_kernel<<<NIMG, 1024, 0, stream>>>(cand, candcnt, reg_all,
                                          (const float*)d_in[30], (float*)d_out);
}